// Round 6
// baseline (98.980 us; speedup 1.0000x reference)
//
#include <hip/hip_runtime.h>

// IDW, POWER=2.0 -> w = 1/d2 (sqrt cancels). out = sum(w*v)/sum(w).
// B=2, P=131072, S=512.
// R11 (DIAGNOSTIC round): 5 rounds bracket the space; back-solved kernel
//   time is flat ~39-44us across {LDS|SMEM} x {1|2|4 waves/SIMD} x
//   {rot|direct} -- insensitive to datapath, occupancy, pipeline depth;
//   sensitive ONLY to instruction mix (R9: +3 rcp/quad -> +8.6us => ~13cyc
//   per exposed wave64 trans). That is the signature of a fixed
//   per-instruction rate ~2.8x the 2cyc/wave-inst model, i.e. either
//   (A) low effective core clock (DVFS parked after the 40us memory-bound
//       fill; 13.2us@2.4GHz == 37us@~850MHz -- matches), or
//   (B) a structural stall never seen because idw_kernel has NEVER appeared
//       in the top-5 counter table (it sits just under the ~40us fills).
//   This round: GPT=8 / 128 blocks. Math bit-identical (guaranteed pass);
//   kernel ~2x -> becomes #1 dispatch -> we get VALUBusy/Occupancy/LDS
//   counters for idw itself.
//   Pre-committed read: VALUBusy>=80% => theory A (next: cut total issue
//   ops: expansion d2, f64-MFMA offload). VALUBusy~35-40% => theory B
//   (attack whichever stall the counters reveal).
// Math unchanged from R6/R10: 4-way rcp-combine, 31 VALU + 1 trans per
//   4 stations/point; EPS2 folded into the d2 fma chain.

#define BLOCK 256
#define S_MAX 512
#define GPT 8

__global__ __launch_bounds__(BLOCK) void idw_kernel(
    const float* __restrict__ station_coords,  // (B, S, 2)
    const float* __restrict__ station_values,  // (B, S)
    const float* __restrict__ grid_points,     // (B, P, 2)
    float* __restrict__ out,                   // (B, P)
    int P, int S) {

    __shared__ float st[S_MAX * 3];  // packed {x,y,v}, 12B/station

    const int b = blockIdx.y;
    const float2* __restrict__ sc2 = (const float2*)(station_coords) + (size_t)b * S;
    const float*  __restrict__ svb = station_values + (size_t)b * S;

    for (int i = threadIdx.x; i < S; i += BLOCK) {
        const float2 c = sc2[i];
        st[3 * i + 0] = c.x;
        st[3 * i + 1] = c.y;
        st[3 * i + 2] = svb[i];
    }
    __syncthreads();

    const int tid = blockIdx.x * BLOCK + threadIdx.x;
    // 8 points per thread: 4 coalesced float4 loads.
    const float4* __restrict__ gp4 = (const float4*)grid_points + (size_t)b * (P / 2);
    const float4 ga = gp4[4 * tid + 0];
    const float4 gb = gp4[4 * tid + 1];
    const float4 gc = gp4[4 * tid + 2];
    const float4 gd = gp4[4 * tid + 3];
    const float gx0 = ga.x, gy0 = ga.y, gx1 = ga.z, gy1 = ga.w;
    const float gx2 = gb.x, gy2 = gb.y, gx3 = gb.z, gy3 = gb.w;
    const float gx4 = gc.x, gy4 = gc.y, gx5 = gc.z, gy5 = gc.w;
    const float gx6 = gd.x, gy6 = gd.y, gx7 = gd.z, gy7 = gd.w;

    constexpr float EPS  = 1.1920928955078125e-07f;
    constexpr float EPS2 = EPS * EPS;

    float ws0 = 0.0f, vs0 = 0.0f, ws1 = 0.0f, vs1 = 0.0f;
    float ws2 = 0.0f, vs2 = 0.0f, ws3 = 0.0f, vs3 = 0.0f;
    float ws4 = 0.0f, vs4 = 0.0f, ws5 = 0.0f, vs5 = 0.0f;
    float ws6 = 0.0f, vs6 = 0.0f, ws7 = 0.0f, vs7 = 0.0f;

    const float4* __restrict__ st4 = (const float4*)st;

    // 4 stations A,B,C,D vs one point: ~31 plain VALU + 1 rcp (R6 math).
    // layout: f0 = Ax Ay Av Bx | f1 = By Bv Cx Cy | f2 = Cv Dx Dy Dv
    auto quad = [&](float gx, float gy, float& ws, float& vs,
                    const float4& f0, const float4& f1, const float4& f2) {
        const float dxa = gx - f0.x, dya = gy - f0.y;
        const float a = fmaf(dxa, dxa, fmaf(dya, dya, EPS2));
        const float dxb = gx - f0.w, dyb = gy - f1.x;
        const float bq = fmaf(dxb, dxb, fmaf(dyb, dyb, EPS2));
        const float dxc = gx - f1.z, dyc = gy - f1.w;
        const float c = fmaf(dxc, dxc, fmaf(dyc, dyc, EPS2));
        const float dxd = gx - f2.y, dyd = gy - f2.z;
        const float d = fmaf(dxd, dxd, fmaf(dyd, dyd, EPS2));
        const float pab = a * bq, pcd = c * d;
        const float sab = a + bq, scd = c + d;
        const float nab = fmaf(f1.y, a, f0.z * bq);  // vB*a + vA*b
        const float ncd = fmaf(f2.w, c, f2.x * d);   // vD*c + vC*d
        const float r = __builtin_amdgcn_rcpf(pab * pcd);
        ws = fmaf(fmaf(sab, pcd, scd * pab), r, ws);
        vs = fmaf(fmaf(nab, pcd, ncd * pab), r, vs);
    };

#pragma unroll 2
    for (int k = 0; k < S_MAX / 4; ++k) {
        const float4 f0 = st4[3 * k + 0];
        const float4 f1 = st4[3 * k + 1];
        const float4 f2 = st4[3 * k + 2];
        quad(gx0, gy0, ws0, vs0, f0, f1, f2);
        quad(gx1, gy1, ws1, vs1, f0, f1, f2);
        quad(gx2, gy2, ws2, vs2, f0, f1, f2);
        quad(gx3, gy3, ws3, vs3, f0, f1, f2);
        quad(gx4, gy4, ws4, vs4, f0, f1, f2);
        quad(gx5, gy5, ws5, vs5, f0, f1, f2);
        quad(gx6, gy6, ws6, vs6, f0, f1, f2);
        quad(gx7, gy7, ws7, vs7, f0, f1, f2);
    }

    float4* __restrict__ out4 = (float4*)out + (size_t)b * (P / 4);
    out4[2 * tid + 0] = make_float4(vs0 / ws0, vs1 / ws1, vs2 / ws2, vs3 / ws3);
    out4[2 * tid + 1] = make_float4(vs4 / ws4, vs5 / ws5, vs6 / ws6, vs7 / ws7);
}

extern "C" void kernel_launch(void* const* d_in, const int* in_sizes, int n_in,
                              void* d_out, int out_size, void* d_ws, size_t ws_size,
                              hipStream_t stream) {
    const float* station_coords = (const float*)d_in[0];
    const float* station_values = (const float*)d_in[1];
    const float* grid_points    = (const float*)d_in[2];
    float* out = (float*)d_out;

    const int B = 2;
    const int S = in_sizes[1] / B;   // 512
    const int P = out_size / B;      // 131072

    dim3 grid(P / (BLOCK * GPT), B);  // 64 x 2 = 128 blocks (diagnostic)
    dim3 block(BLOCK);
    idw_kernel<<<grid, block, 0, stream>>>(station_coords, station_values,
                                           grid_points, out, P, S);
}

// Round 7
// 80.948 us; speedup vs baseline: 1.2228x; 1.2228x over previous
//
#include <hip/hip_runtime.h>

// IDW, POWER=2.0 -> w = 1/d2 (sqrt cancels). out = sum(w*v)/sum(w).
// B=2, P=131072, S=512.
// R12: R11 diagnostic landed the kernel in the counter table:
//   46.6us, VALUBusy 29.4% chip-wide at HALF-occupied chip (128 blocks) =>
//   ~59% issue duty on active SIMDs; model closes: 65536 cyc/wave / 0.59 =
//   46.3us. Clock theory dead. R11's structure is 1.66x more efficient
//   per-CU than R10 (43.9 vs 26.5 pts/us): the win was the 256-inst ILP
//   window (8 independent quads) + direct-indexed loads the compiler
//   pipelines across the unroll. Its total was bad only because half the
//   CUs were idle.
//   This round: same structure at FULL chip. threads*GPT = 262144 fixes
//   GPT=4 / 256 blocks as the only 1-wave/SIMD full-chip config; recover
//   the ILP window via #pragma unroll 4 (4 chunks x 4 quads = 512-inst
//   window, 12 hoistable ds_read_b128) -- window size, not live-point
//   count, is what bought R11 its duty.
//   Arithmetic: 32768 VALU-cyc/SIMD = 13.65us @100% duty; at 59% -> ~23us.
//   Predict total 63-68us (idw drops back below the 40us fills in top-5).
//   Fallback if flat: split station axis (partial sums are additive).
// Math unchanged (bit-identical since R6): 4-way rcp-combine, 31 VALU +
//   1 trans per 4 stations/point; EPS2 folded into the d2 fma chain.

#define BLOCK 256
#define S_MAX 512
#define GPT 4

__global__ __launch_bounds__(BLOCK) void idw_kernel(
    const float* __restrict__ station_coords,  // (B, S, 2)
    const float* __restrict__ station_values,  // (B, S)
    const float* __restrict__ grid_points,     // (B, P, 2)
    float* __restrict__ out,                   // (B, P)
    int P, int S) {

    __shared__ float st[S_MAX * 3];  // packed {x,y,v}, 12B/station

    const int b = blockIdx.y;
    const float2* __restrict__ sc2 = (const float2*)(station_coords) + (size_t)b * S;
    const float*  __restrict__ svb = station_values + (size_t)b * S;

    for (int i = threadIdx.x; i < S; i += BLOCK) {
        const float2 c = sc2[i];
        st[3 * i + 0] = c.x;
        st[3 * i + 1] = c.y;
        st[3 * i + 2] = svb[i];
    }
    __syncthreads();

    const int tid = blockIdx.x * BLOCK + threadIdx.x;
    // 4 points per thread: 2 coalesced float4 loads.
    const float4* __restrict__ gp4 = (const float4*)grid_points + (size_t)b * (P / 2);
    const float4 ga = gp4[2 * tid + 0];
    const float4 gb = gp4[2 * tid + 1];
    const float gx0 = ga.x, gy0 = ga.y, gx1 = ga.z, gy1 = ga.w;
    const float gx2 = gb.x, gy2 = gb.y, gx3 = gb.z, gy3 = gb.w;

    constexpr float EPS  = 1.1920928955078125e-07f;
    constexpr float EPS2 = EPS * EPS;

    float ws0 = 0.0f, vs0 = 0.0f, ws1 = 0.0f, vs1 = 0.0f;
    float ws2 = 0.0f, vs2 = 0.0f, ws3 = 0.0f, vs3 = 0.0f;

    const float4* __restrict__ st4 = (const float4*)st;

    // 4 stations A,B,C,D vs one point: ~31 plain VALU + 1 rcp (R6 math).
    // layout: f0 = Ax Ay Av Bx | f1 = By Bv Cx Cy | f2 = Cv Dx Dy Dv
    auto quad = [&](float gx, float gy, float& ws, float& vs,
                    const float4& f0, const float4& f1, const float4& f2) {
        const float dxa = gx - f0.x, dya = gy - f0.y;
        const float a = fmaf(dxa, dxa, fmaf(dya, dya, EPS2));
        const float dxb = gx - f0.w, dyb = gy - f1.x;
        const float bq = fmaf(dxb, dxb, fmaf(dyb, dyb, EPS2));
        const float dxc = gx - f1.z, dyc = gy - f1.w;
        const float c = fmaf(dxc, dxc, fmaf(dyc, dyc, EPS2));
        const float dxd = gx - f2.y, dyd = gy - f2.z;
        const float d = fmaf(dxd, dxd, fmaf(dyd, dyd, EPS2));
        const float pab = a * bq, pcd = c * d;
        const float sab = a + bq, scd = c + d;
        const float nab = fmaf(f1.y, a, f0.z * bq);  // vB*a + vA*b
        const float ncd = fmaf(f2.w, c, f2.x * d);   // vD*c + vC*d
        const float r = __builtin_amdgcn_rcpf(pab * pcd);
        ws = fmaf(fmaf(sab, pcd, scd * pab), r, ws);
        vs = fmaf(fmaf(nab, pcd, ncd * pab), r, vs);
    };

#pragma unroll 4
    for (int k = 0; k < S_MAX / 4; ++k) {
        const float4 f0 = st4[3 * k + 0];
        const float4 f1 = st4[3 * k + 1];
        const float4 f2 = st4[3 * k + 2];
        quad(gx0, gy0, ws0, vs0, f0, f1, f2);
        quad(gx1, gy1, ws1, vs1, f0, f1, f2);
        quad(gx2, gy2, ws2, vs2, f0, f1, f2);
        quad(gx3, gy3, ws3, vs3, f0, f1, f2);
    }

    const float4 res = make_float4(vs0 / ws0, vs1 / ws1, vs2 / ws2, vs3 / ws3);
    ((float4*)out)[(size_t)b * (P / 4) + tid] = res;
}

extern "C" void kernel_launch(void* const* d_in, const int* in_sizes, int n_in,
                              void* d_out, int out_size, void* d_ws, size_t ws_size,
                              hipStream_t stream) {
    const float* station_coords = (const float*)d_in[0];
    const float* station_values = (const float*)d_in[1];
    const float* grid_points    = (const float*)d_in[2];
    float* out = (float*)d_out;

    const int B = 2;
    const int S = in_sizes[1] / B;   // 512
    const int P = out_size / B;      // 131072

    dim3 grid(P / (BLOCK * GPT), B);  // 128 x 2 = 256 blocks, 1/CU full chip
    dim3 block(BLOCK);
    idw_kernel<<<grid, block, 0, stream>>>(station_coords, station_values,
                                           grid_points, out, P, S);
}